// Round 3
// baseline (542.259 us; speedup 1.0000x reference)
//
#include <hip/hip_runtime.h>
#include <stdint.h>

#define EMBED 1024
#define TOKLEN 100
#define TOKDIM 256
#define MLPD 128
#define KEXT 1152   // 1024 body + 128 attn (100 real + 28 zero)

typedef float f32x4 __attribute__((ext_vector_type(4)));
typedef __bf16 bf16x8 __attribute__((ext_vector_type(8)));

__device__ __forceinline__ unsigned short f2bf(float f) {
  unsigned int u = __float_as_uint(f);
  u += 0x7fffu + ((u >> 16) & 1);   // RNE
  return (unsigned short)(u >> 16);
}
__device__ __forceinline__ float bf2f(unsigned short h) {
  return __uint_as_float(((unsigned int)h) << 16);
}
__device__ __forceinline__ void async16(const void* g, void* l) {
  __builtin_amdgcn_global_load_lds(
      (const __attribute__((address_space(1))) unsigned int*)g,
      (__attribute__((address_space(3))) unsigned int*)l, 16, 0, 0);
}

// T2 LDS XOR-swizzle: pre-swizzled SOURCE chunk (schunk^srow) for the linear
// global_load_lds write; same involution ((ks*4+quad)^(row&7)) on ds_read.
// R1 verified: bank conflicts 2.83e7 -> 0.

// ---------------- small precompute chain ----------------

__global__ void k_gelu(const float* __restrict__ B, const int* __restrict__ layer,
                       const float* __restrict__ Wd, const float* __restrict__ bd,
                       float* __restrict__ G) {
  int idx = blockIdx.x * 256 + threadIdx.x;      // 0..131071
  int c = idx >> 7, j = idx & 127;
  const float* bl = B + ((size_t)layer[0] * EMBED + c) * TOKDIM;
  const float* wd = Wd + (size_t)j * TOKDIM;
  float a0 = 0.f, a1 = 0.f, a2 = 0.f, a3 = 0.f;
  for (int k = 0; k < TOKDIM; k += 4) {
    float4 a = *(const float4*)(bl + k);
    float4 b = *(const float4*)(wd + k);
    a0 += a.x * b.x; a1 += a.y * b.y; a2 += a.z * b.z; a3 += a.w * b.w;
  }
  float v = a0 + a1 + a2 + a3 + bd[j];
  G[idx] = 0.5f * v * (1.f + erff(v * 0.70710678118654752440f));
}

__global__ void k_ag(const float* __restrict__ A, const float* __restrict__ G,
                     float* __restrict__ AG, float* __restrict__ asum) {
  int m = blockIdx.x, j = threadIdx.x;           // 100 blocks x 128 thr
  const float* a = A + (size_t)m * EMBED;
  float acc = 0.f, s = 0.f;
  for (int c = 0; c < EMBED; ++c) acc += a[c] * G[(size_t)c * MLPD + j];
  AG[(size_t)m * MLPD + j] = acc;
  for (int c = j; c < EMBED; c += 128) s += a[c];
  __shared__ float red[128];
  red[j] = s; __syncthreads();
  for (int w = 64; w > 0; w >>= 1) { if (j < w) red[j] += red[j + w]; __syncthreads(); }
  if (j == 0) asum[m] = red[0];
}

__global__ void k_tokens(const float* __restrict__ AG, const float* __restrict__ asum,
                         const float* __restrict__ Wu, const float* __restrict__ bu,
                         unsigned short* __restrict__ tokbf) {
  int m = blockIdx.x, t = threadIdx.x;           // 128 blocks x 256 thr
  if (m >= TOKLEN) {
    #pragma unroll
    for (int i = 0; i < 4; ++i) tokbf[(size_t)m * EMBED + t * 4 + i] = 0;
    return;
  }
  __shared__ float ag[MLPD];
  __shared__ float as_s;
  if (t < MLPD) ag[t] = AG[(size_t)m * MLPD + t];
  if (t == 0) as_s = asum[m];
  __syncthreads();
  #pragma unroll
  for (int i = 0; i < 4; ++i) {
    int e = t * 4 + i;
    const float* wu = Wu + (size_t)e * MLPD;
    float a0 = 0.f, a1 = 0.f, a2 = 0.f, a3 = 0.f;
    for (int j = 0; j < MLPD; j += 4) {
      float4 w = *(const float4*)(wu + j);
      a0 += w.x * ag[j]; a1 += w.y * ag[j + 1]; a2 += w.z * ag[j + 2]; a3 += w.w * ag[j + 3];
    }
    tokbf[(size_t)m * EMBED + e] = f2bf(a0 + a1 + a2 + a3 + as_s * bu[e]);
  }
}

// Fused Wf/Wt precompute
__global__ void k_wprep(const float* __restrict__ Wf, const float* __restrict__ Wt,
                        const float* __restrict__ bt,
                        unsigned short* __restrict__ Bt, unsigned short* __restrict__ wfbf,
                        unsigned short* __restrict__ wtbf, float* __restrict__ wfbt) {
  int e = blockIdx.x, t = threadIdx.x;           // 1024 blocks x 256 thr
  float4 v = *(const float4*)(Wf + (size_t)e * EMBED + t * 4);
  uint2 u;
  u.x = (unsigned int)f2bf(v.x) | ((unsigned int)f2bf(v.y) << 16);
  u.y = (unsigned int)f2bf(v.z) | ((unsigned int)f2bf(v.w) << 16);
  *(uint2*)(Bt + (size_t)e * KEXT + t * 4) = u;
  *(uint2*)(wfbf + (size_t)e * EMBED + t * 4) = u;
  if (t < 28) Bt[(size_t)e * KEXT + 1124 + t] = 0;
  float4 w = *(const float4*)(Wt + (size_t)e * EMBED + t * 4);
  uint2 u2;
  u2.x = (unsigned int)f2bf(w.x) | ((unsigned int)f2bf(w.y) << 16);
  u2.y = (unsigned int)f2bf(w.z) | ((unsigned int)f2bf(w.w) << 16);
  *(uint2*)(wtbf + (size_t)e * EMBED + t * 4) = u2;
  float4 b = *(const float4*)(bt + t * 4);
  __shared__ float red[256];
  red[t] = v.x * b.x + v.y * b.y + v.z * b.z + v.w * b.w;
  __syncthreads();
  for (int s = 128; s > 0; s >>= 1) { if (t < s) red[t] += red[t + s]; __syncthreads(); }
  if (t == 0) wfbt[e] = red[0];
}

__global__ void k_cls(const float* __restrict__ x, float* __restrict__ out) {
  int i = blockIdx.x * 256 + threadIdx.x;        // 8 blocks: 8192 floats
  ((float4*)out)[i] = ((const float4*)x)[i];
}

// ---------------- tfeat path: two MFMA GEMMs (2-phase dbuf) ----------------

__global__ void __launch_bounds__(256) k_tf1(const unsigned short* __restrict__ tokbf,
                                             const unsigned short* __restrict__ wtbf,
                                             unsigned short* __restrict__ tfeatbf) {
  __shared__ unsigned short As[2][128 * 64];
  __shared__ unsigned short Bs[2][128 * 64];
  const int tid = threadIdx.x;
  const int wave = tid >> 6, lane = tid & 63;
  const int l15 = lane & 15, quad = lane >> 4;
  const int srow = lane >> 3, schunk = lane & 7;
  const int col0 = blockIdx.x * 128;
  const int wr = (wave >> 1) * 64, wc = (wave & 1) * 64;

  f32x4 acc[4][4];
  const f32x4 zero = {0.f, 0.f, 0.f, 0.f};
  #pragma unroll
  for (int i = 0; i < 4; ++i)
    #pragma unroll
    for (int j = 0; j < 4; ++j) acc[i][j] = zero;

  auto stage = [&](int buf, int kt) {
    const int k0 = kt * 64;
    #pragma unroll
    for (int i = 0; i < 4; ++i) {
      const int r = i * 32 + wave * 8;
      async16(tokbf + (size_t)(r + srow) * EMBED + k0 + (schunk ^ srow) * 8, &As[buf][r * 64]);
      async16(wtbf + (size_t)(col0 + r + srow) * EMBED + k0 + (schunk ^ srow) * 8, &Bs[buf][r * 64]);
    }
  };
  auto compute = [&](int buf) {
    #pragma unroll
    for (int ks = 0; ks < 2; ++ks) {
      const int sw = ((ks * 4 + quad) ^ (l15 & 7)) * 8;
      bf16x8 a[4], b[4];
      #pragma unroll
      for (int i = 0; i < 4; ++i)
        a[i] = *(const bf16x8*)&As[buf][(wr + i * 16 + l15) * 64 + sw];
      #pragma unroll
      for (int j = 0; j < 4; ++j)
        b[j] = *(const bf16x8*)&Bs[buf][(wc + j * 16 + l15) * 64 + sw];
      #pragma unroll
      for (int i = 0; i < 4; ++i)
        #pragma unroll
        for (int j = 0; j < 4; ++j)
          acc[i][j] = __builtin_amdgcn_mfma_f32_16x16x32_bf16(a[i], b[j], acc[i][j], 0, 0, 0);
    }
  };

  stage(0, 0);
  asm volatile("s_waitcnt vmcnt(0)" ::: "memory");
  __syncthreads();
  int cur = 0;
  for (int kt = 0; kt < 16; ++kt) {
    if (kt < 15) stage(cur ^ 1, kt + 1);
    compute(cur);
    asm volatile("s_waitcnt vmcnt(0)" ::: "memory");
    __syncthreads();
    cur ^= 1;
  }
  #pragma unroll
  for (int j = 0; j < 4; ++j) {
    const int e = col0 + wc + j * 16 + l15;
    #pragma unroll
    for (int i = 0; i < 4; ++i) {
      const int mb = wr + i * 16 + quad * 4;
      #pragma unroll
      for (int r = 0; r < 4; ++r)
        tfeatbf[(size_t)(mb + r) * EMBED + e] = f2bf(acc[i][j][r]);
    }
  }
}

__global__ void __launch_bounds__(256) k_tf2(const unsigned short* __restrict__ wfbf,
                                             const unsigned short* __restrict__ tfeatbf,
                                             const float* __restrict__ wfbt,
                                             unsigned short* __restrict__ Bt) {
  __shared__ unsigned short As[2][128 * 64];
  __shared__ unsigned short Bs[2][128 * 64];
  const int tid = threadIdx.x;
  const int wave = tid >> 6, lane = tid & 63;
  const int l15 = lane & 15, quad = lane >> 4;
  const int srow = lane >> 3, schunk = lane & 7;
  const int row0 = blockIdx.x * 128;
  const int wr = (wave >> 1) * 64, wc = (wave & 1) * 64;

  f32x4 acc[4][4];
  const f32x4 zero = {0.f, 0.f, 0.f, 0.f};
  #pragma unroll
  for (int i = 0; i < 4; ++i)
    #pragma unroll
    for (int j = 0; j < 4; ++j) acc[i][j] = zero;

  auto stage = [&](int buf, int kt) {
    const int k0 = kt * 64;
    #pragma unroll
    for (int i = 0; i < 4; ++i) {
      const int r = i * 32 + wave * 8;
      async16(wfbf + (size_t)(row0 + r + srow) * EMBED + k0 + (schunk ^ srow) * 8, &As[buf][r * 64]);
      async16(tfeatbf + (size_t)(r + srow) * EMBED + k0 + (schunk ^ srow) * 8, &Bs[buf][r * 64]);
    }
  };
  auto compute = [&](int buf) {
    #pragma unroll
    for (int ks = 0; ks < 2; ++ks) {
      const int sw = ((ks * 4 + quad) ^ (l15 & 7)) * 8;
      bf16x8 a[4], b[4];
      #pragma unroll
      for (int i = 0; i < 4; ++i)
        a[i] = *(const bf16x8*)&As[buf][(wr + i * 16 + l15) * 64 + sw];
      #pragma unroll
      for (int j = 0; j < 4; ++j)
        b[j] = *(const bf16x8*)&Bs[buf][(wc + j * 16 + l15) * 64 + sw];
      #pragma unroll
      for (int i = 0; i < 4; ++i)
        #pragma unroll
        for (int j = 0; j < 4; ++j)
          acc[i][j] = __builtin_amdgcn_mfma_f32_16x16x32_bf16(a[i], b[j], acc[i][j], 0, 0, 0);
    }
  };

  stage(0, 0);
  asm volatile("s_waitcnt vmcnt(0)" ::: "memory");
  __syncthreads();
  int cur = 0;
  for (int kt = 0; kt < 16; ++kt) {
    if (kt < 15) stage(cur ^ 1, kt + 1);
    compute(cur);
    asm volatile("s_waitcnt vmcnt(0)" ::: "memory");
    __syncthreads();
    cur ^= 1;
  }
  #pragma unroll
  for (int j = 0; j < 4; ++j) {
    const int m = wc + j * 16 + l15;
    #pragma unroll
    for (int i = 0; i < 4; ++i) {
      const int eb = row0 + wr + i * 16 + quad * 4;
      #pragma unroll
      for (int r = 0; r < 4; ++r)
        Bt[(size_t)(eb + r) * KEXT + 1024 + m] = f2bf(acc[i][j][r] + wfbt[eb + r]);
    }
  }
}

// ---------------- attention scores + softmax -> A_ext ----------------
__global__ void __launch_bounds__(256) k_attn(const float* __restrict__ x,
                                              const unsigned short* __restrict__ tokbf,
                                              unsigned short* __restrict__ Aext) {
  __shared__ __align__(16) unsigned short smem[2 * 128 * 72 + 2 * 128 * 64];
  const int tid = threadIdx.x;
  const int wave = tid >> 6, lane = tid & 63;
  const int l15 = lane & 15, quad = lane >> 4;
  const int srow = lane >> 3, schunk = lane & 7;
  const int row0 = blockIdx.x * 128;
  const int trow = tid >> 1, thalf = tid & 1;
  const float* body = x + 8 * EMBED;
  const float* gxbase = body + (size_t)(row0 + trow) * EMBED + thalf * 32;

  f32x4 acc[2][8];
  const f32x4 zero = {0.f, 0.f, 0.f, 0.f};
  #pragma unroll
  for (int i = 0; i < 2; ++i)
    #pragma unroll
    for (int j = 0; j < 8; ++j) acc[i][j] = zero;

  float4 v[8];

  auto regload = [&](int kt) {
    const float* gx = gxbase + kt * 64;
    #pragma unroll
    for (int q = 0; q < 8; ++q) v[q] = *(const float4*)(gx + q * 4);
  };
  auto tsstage = [&](int buf, int kt) {
    unsigned short* Ts = smem + 2 * 128 * 72 + buf * (128 * 64);
    const int k0 = kt * 64;
    #pragma unroll
    for (int i = 0; i < 4; ++i) {
      const int r = i * 32 + wave * 8;
      async16(tokbf + (size_t)(r + srow) * EMBED + k0 + (schunk ^ srow) * 8, &Ts[r * 64]);
    }
  };
  auto convwrite = [&](int buf, int kt) {
    unsigned short* As = smem + buf * (128 * 72);
    unsigned int pk[16];
    #pragma unroll
    for (int q = 0; q < 8; ++q) {
      pk[q * 2]     = (unsigned int)f2bf(v[q].x) | ((unsigned int)f2bf(v[q].y) << 16);
      pk[q * 2 + 1] = (unsigned int)f2bf(v[q].z) | ((unsigned int)f2bf(v[q].w) << 16);
    }
    unsigned int* lw = (unsigned int*)&As[trow * 72 + thalf * 32];
    unsigned int* gw = (unsigned int*)(Aext + (size_t)(row0 + trow) * KEXT + kt * 64 + thalf * 32);
    #pragma unroll
    for (int q = 0; q < 4; ++q) {
      uint4 u; u.x = pk[q*4]; u.y = pk[q*4+1]; u.z = pk[q*4+2]; u.w = pk[q*4+3];
      ((uint4*)lw)[q] = u;
      ((uint4*)gw)[q] = u;
    }
  };
  auto compute = [&](int buf) {
    unsigned short* As = smem + buf * (128 * 72);
    unsigned short* Ts = smem + 2 * 128 * 72 + buf * (128 * 64);
    #pragma unroll
    for (int ks = 0; ks < 2; ++ks) {
      const int sw = ((ks * 4 + quad) ^ (l15 & 7)) * 8;
      bf16x8 a[2], b[8];
      #pragma unroll
      for (int i = 0; i < 2; ++i)
        a[i] = *(const bf16x8*)&As[(wave * 32 + i * 16 + l15) * 72 + ks * 32 + quad * 8];
      #pragma unroll
      for (int j = 0; j < 8; ++j)
        b[j] = *(const bf16x8*)&Ts[(j * 16 + l15) * 64 + sw];
      #pragma unroll
      for (int i = 0; i < 2; ++i)
        #pragma unroll
        for (int j = 0; j < 8; ++j)
          acc[i][j] = __builtin_amdgcn_mfma_f32_16x16x32_bf16(a[i], b[j], acc[i][j], 0, 0, 0);
    }
  };

  regload(0); tsstage(0, 0);
  asm volatile("s_waitcnt vmcnt(0)" ::: "memory");
  convwrite(0, 0);
  __syncthreads();
  int cur = 0;
  for (int kt = 0; kt < 16; ++kt) {
    if (kt < 15) { regload(kt + 1); tsstage(cur ^ 1, kt + 1); }
    compute(cur);
    if (kt < 15) {
      asm volatile("s_waitcnt vmcnt(0)" ::: "memory");
      convwrite(cur ^ 1, kt + 1);
    }
    __syncthreads();
    cur ^= 1;
  }

  unsigned short* Sc = smem;
  #pragma unroll
  for (int i = 0; i < 2; ++i) {
    #pragma unroll
    for (int r = 0; r < 4; ++r) {
      float mx = -1e30f;
      #pragma unroll
      for (int j = 0; j < 8; ++j) {
        const int c = j * 16 + l15;
        const float vv = acc[i][j][r] * 0.03125f;
        if (c < TOKLEN) mx = fmaxf(mx, vv);
      }
      #pragma unroll
      for (int d = 1; d < 16; d <<= 1) mx = fmaxf(mx, __shfl_xor(mx, d));
      float sm = 0.f;
      #pragma unroll
      for (int j = 0; j < 8; ++j) {
        const int c = j * 16 + l15;
        if (c < TOKLEN) sm += __expf(acc[i][j][r] * 0.03125f - mx);
      }
      #pragma unroll
      for (int d = 1; d < 16; d <<= 1) sm += __shfl_xor(sm, d);
      const float inv = 1.f / sm;
      const int row = wave * 32 + i * 16 + quad * 4 + r;
      #pragma unroll
      for (int j = 0; j < 8; ++j) {
        const int c = j * 16 + l15;
        const float p = (c < TOKLEN) ? __expf(acc[i][j][r] * 0.03125f - mx) * inv : 0.f;
        Sc[row * 128 + c] = f2bf(p);
      }
    }
  }
  __syncthreads();
  {
    const int r = tid >> 1, h = tid & 1;
    const uint4* src = (const uint4*)(Sc + r * 128 + h * 64);
    uint4* dst = (uint4*)(Aext + (size_t)(row0 + r) * KEXT + 1024 + h * 64);
    dst[0] = src[0]; dst[1] = src[1]; dst[2] = src[2]; dst[3] = src[3];
  }
}

// ---------------- main GEMM: 256x256 tile, 8-phase schedule (T2+T3+T4+T5) ----
// C = A_ext(32768x1152) @ Bt(1024x1152)^T. Grid 512 = 128 rowtiles x 4 coltiles,
// XCD-aware. 512 thr = 8 waves (2M x 4N), per-wave C = 128x64. LDS 128KB:
// 2 sets x {A 2x(128x64), B 2x(128x64)} bf16. K-tile t -> set t&1.
// Per K-tile: 4 quadrant phases {12 ds_read_b128, s_barrier, setprio(1),
// 16 MFMA, setprio(0), s_barrier}. Raw s_barrier (NOT __syncthreads) so
// staging loads stay in flight. Whole next K-tile (8 gload_lds/thread)
// issued right after each boundary; boundary vmcnt(0) thus waits on loads
// issued 4 phases (~800cy) earlier -> no exposed latency.

#define MAIN_PHASE(S, MH, NH)                                                   \
  do {                                                                          \
    bf16x8 pa0, pa1, pa2, pa3, pb0, pb1, pa4, pa5, pa6, pa7, pb2, pb3;          \
    {                                                                           \
      const int sw0 = ((0 * 4 + quad) ^ (l15 & 7)) * 8;                         \
      const int sw1 = ((1 * 4 + quad) ^ (l15 & 7)) * 8;                         \
      const unsigned short* Ah = &Ab[S][wm][0];                                 \
      const unsigned short* Bh = &Bb[S][bh][0];                                 \
      pa0 = *(const bf16x8*)&Ah[((MH)*64 + 0*16 + l15) * 64 + sw0];             \
      pa1 = *(const bf16x8*)&Ah[((MH)*64 + 1*16 + l15) * 64 + sw0];             \
      pa2 = *(const bf16x8*)&Ah[((MH)*64 + 2*16 + l15) * 64 + sw0];             \
      pa3 = *(const bf16x8*)&Ah[((MH)*64 + 3*16 + l15) * 64 + sw0];             \
      pb0 = *(const bf16x8*)&Bh[(brb + (NH)*32 + 0*16 + l15) * 64 + sw0];       \
      pb1 = *(const bf16x8*)&Bh[(brb + (NH)*32 + 1*16 + l15) * 64 + sw0];       \
      pa4 = *(const bf16x8*)&Ah[((MH)*64 + 0*16 + l15) * 64 + sw1];             \
      pa5 = *(const bf16x8*)&Ah[((MH)*64 + 1*16 + l15) * 64 + sw1];             \
      pa6 = *(const bf16x8*)&Ah[((MH)*64 + 2*16 + l15) * 64 + sw1];             \
      pa7 = *(const bf16x8*)&Ah[((MH)*64 + 3*16 + l15) * 64 + sw1];             \
      pb2 = *(const bf16x8*)&Bh[(brb + (NH)*32 + 0*16 + l15) * 64 + sw1];       \
      pb3 = *(const bf16x8*)&Bh[(brb + (NH)*32 + 1*16 + l15) * 64 + sw1];       \
    }                                                                           \
    asm volatile("s_barrier" ::: "memory");                                     \
    __builtin_amdgcn_s_setprio(1);                                              \
    acc[(MH)*4+0][(NH)*2+0] = __builtin_amdgcn_mfma_f32_16x16x32_bf16(pa0, pb0, acc[(MH)*4+0][(NH)*2+0], 0, 0, 0); \
    acc[(MH)*4+1][(NH)*2+0] = __builtin_amdgcn_mfma_f32_16x16x32_bf16(pa1, pb0, acc[(MH)*4+1][(NH)*2+0], 0, 0, 0); \
    acc[(MH)*4+2][(NH)*2+0] = __builtin_amdgcn_mfma_f32_16x16x32_bf16(pa2, pb0, acc[(MH)*4+2][(NH)*2+0], 0, 0, 0); \
    acc[(MH)*4+3][(NH)*2+0] = __builtin_amdgcn_mfma_f32_16x16x32_bf16(pa3, pb0, acc[(MH)*4+3][(NH)*2+0], 0, 0, 0); \
    acc[(MH)*4+0][(NH)*2+1] = __builtin_amdgcn_mfma_f32_16x16x32_bf16(pa0, pb1, acc[(MH)*4+0][(NH)*2+1], 0, 0, 0); \
    acc[(MH)*4+1][(NH)*2+1] = __builtin_amdgcn_mfma_f32_16x16x32_bf16(pa1, pb1, acc[(MH)*4+1][(NH)*2+1], 0, 0, 0); \
    acc[(MH)*4+2][(NH)*2+1] = __builtin_amdgcn_mfma_f32_16x16x32_bf16(pa2, pb1, acc[(MH)*4+2][(NH)*2+1], 0, 0, 0); \
    acc[(MH)*4+3][(NH)*2+1] = __builtin_amdgcn_mfma_f32_16x16x32_bf16(pa3, pb1, acc[(MH)*4+3][(NH)*2+1], 0, 0, 0); \
    acc[(MH)*4+0][(NH)*2+0] = __builtin_amdgcn_mfma_f32_16x16x32_bf16(pa4, pb2, acc[(MH)*4+0][(NH)*2+0], 0, 0, 0); \
    acc[(MH)*4+1][(NH)*2+0] = __builtin_amdgcn_mfma_f32_16x16x32_bf16(pa5, pb2, acc[(MH)*4+1][(NH)*2+0], 0, 0, 0); \
    acc[(MH)*4+2][(NH)*2+0] = __builtin_amdgcn_mfma_f32_16x16x32_bf16(pa6, pb2, acc[(MH)*4+2][(NH)*2+0], 0, 0, 0); \
    acc[(MH)*4+3][(NH)*2+0] = __builtin_amdgcn_mfma_f32_16x16x32_bf16(pa7, pb2, acc[(MH)*4+3][(NH)*2+0], 0, 0, 0); \
    acc[(MH)*4+0][(NH)*2+1] = __builtin_amdgcn_mfma_f32_16x16x32_bf16(pa4, pb3, acc[(MH)*4+0][(NH)*2+1], 0, 0, 0); \
    acc[(MH)*4+1][(NH)*2+1] = __builtin_amdgcn_mfma_f32_16x16x32_bf16(pa5, pb3, acc[(MH)*4+1][(NH)*2+1], 0, 0, 0); \
    acc[(MH)*4+2][(NH)*2+1] = __builtin_amdgcn_mfma_f32_16x16x32_bf16(pa6, pb3, acc[(MH)*4+2][(NH)*2+1], 0, 0, 0); \
    acc[(MH)*4+3][(NH)*2+1] = __builtin_amdgcn_mfma_f32_16x16x32_bf16(pa7, pb3, acc[(MH)*4+3][(NH)*2+1], 0, 0, 0); \
    __builtin_amdgcn_s_setprio(0);                                              \
    asm volatile("s_barrier" ::: "memory");                                     \
  } while (0)

#define ISSUE_TILE(KT, S)                                                       \
  do {                                                                          \
    const int k0_ = (KT) * 64;                                                  \
    _Pragma("unroll")                                                           \
    for (int h_ = 0; h_ < 2; ++h_) {                                            \
      _Pragma("unroll")                                                         \
      for (int r2_ = 0; r2_ < 2; ++r2_) {                                       \
        const int rb_ = r2_ * 64 + w8;                                          \
        async16(Aext + (size_t)(row0 + h_ * 128 + rb_ + srow) * KEXT + k0_ + (schunk ^ srow) * 8, \
                &Ab[S][h_][rb_ * 64]);                                          \
        async16(Bt + (size_t)(col0 + h_ * 128 + rb_ + srow) * KEXT + k0_ + (schunk ^ srow) * 8,   \
                &Bb[S][h_][rb_ * 64]);                                          \
      }                                                                         \
    }                                                                           \
  } while (0)

__global__ void __launch_bounds__(512) k_main(const unsigned short* __restrict__ Aext,
                                              const unsigned short* __restrict__ Bt,
                                              const float* __restrict__ x,
                                              const float* __restrict__ bfv,
                                              const float* __restrict__ scale,
                                              float* __restrict__ out) {
  __shared__ unsigned short Ab[2][2][128 * 64];   // [set][M-half][row*64+chunk]
  __shared__ unsigned short Bb[2][2][128 * 64];   // [set][N-half]
  const int tid = threadIdx.x;
  const int w = tid >> 6, lane = tid & 63;
  const int l15 = lane & 15, quad = lane >> 4;
  const int srow = lane >> 3, schunk = lane & 7;
  const int w8 = w * 8;
  const int wm = w >> 2, wn = w & 3;
  const int bh = wn >> 1, brb = (wn & 1) * 64;

  const int xcd = blockIdx.x & 7, slot = blockIdx.x >> 3;
  const int rt = (slot >> 2) * 8 + xcd;           // 0..127
  const int ct = slot & 3;                        // 0..3
  const int row0 = rt * 256;
  const int col0 = ct * 256;

  f32x4 acc[8][4];
  const f32x4 zero = {0.f, 0.f, 0.f, 0.f};
  #pragma unroll
  for (int i = 0; i < 8; ++i)
    #pragma unroll
    for (int j = 0; j < 4; ++j) acc[i][j] = zero;

  ISSUE_TILE(0, 0);
  #pragma unroll 1
  for (int i = 0; i < 9; ++i) {
    // ---- boundary: K-tile 2i (set0) ready ----
    asm volatile("s_waitcnt vmcnt(0)" ::: "memory");
    asm volatile("s_barrier" ::: "memory");
    ISSUE_TILE(2 * i + 1, 1);                     // always <= 17
    MAIN_PHASE(0, 0, 0); MAIN_PHASE(0, 0, 1);
    MAIN_PHASE(0, 1, 0); MAIN_PHASE(0, 1, 1);
    // ---- boundary: K-tile 2i+1 (set1) ready ----
    asm volatile("s_waitcnt vmcnt(0)" ::: "memory");
    asm volatile("s_barrier" ::: "memory");
    if (i < 8) ISSUE_TILE(2 * i + 2, 0);
    MAIN_PHASE(1, 0, 0); MAIN_PHASE(1, 0, 1);
    MAIN_PHASE(1, 1, 0); MAIN_PHASE(1, 1, 1);
  }

  const float s = scale[0];
  #pragma unroll
  for (int mf = 0; mf < 8; ++mf) {
    const int rb = row0 + wm * 128 + mf * 16 + quad * 4;
    #pragma unroll
    for (int nf = 0; nf < 4; ++nf) {
      const int c = col0 + wn * 64 + nf * 16 + l15;
      const float bfc = bfv[c];
      #pragma unroll
      for (int r = 0; r < 4; ++r) {
        const size_t idx = (size_t)(rb + r + 8) * EMBED + c;
        out[idx] = x[idx] + (acc[mf][nf][r] + bfc) * s;
      }
    }
  }
}

extern "C" void kernel_launch(void* const* d_in, const int* in_sizes, int n_in,
                              void* d_out, int out_size, void* d_ws, size_t ws_size,
                              hipStream_t stream) {
  const float* x     = (const float*)d_in[0];
  const int*   layer = (const int*)d_in[1];
  const float* A     = (const float*)d_in[2];
  const float* B     = (const float*)d_in[3];
  const float* Wd    = (const float*)d_in[4];
  const float* bd    = (const float*)d_in[5];
  const float* Wu    = (const float*)d_in[6];
  const float* bu    = (const float*)d_in[7];
  const float* Wt    = (const float*)d_in[8];
  const float* bt    = (const float*)d_in[9];
  const float* Wf    = (const float*)d_in[10];
  const float* bf    = (const float*)d_in[11];
  const float* scale = (const float*)d_in[12];
  float* out = (float*)d_out;

  char* ws = (char*)d_ws;
  unsigned short* Aext    = (unsigned short*)(ws + 0);          // 32768*1152*2
  unsigned short* wtbf    = (unsigned short*)(ws + 0);          // alias (dead before k_attn)
  unsigned short* wfbf    = (unsigned short*)(ws + 2097152);    // alias
  unsigned short* Bt_     = (unsigned short*)(ws + 75497472);   // 1024*1152*2
  unsigned short* tokbf   = (unsigned short*)(ws + 77856768);   // 128*1024*2
  float*          G       = (float*)(ws + 78118912);            // 1024*128*4
  float*          AG      = (float*)(ws + 78643200);            // 100*128*4
  float*          asum    = (float*)(ws + 78694400);            // 128*4
  float*          wfbt    = (float*)(ws + 78694912);            // 1024*4
  unsigned short* tfeatbf = (unsigned short*)(ws + 78699008);   // 128*1024*2

  k_gelu  <<<512, 256, 0, stream>>>(B, layer, Wd, bd, G);
  k_ag    <<<100, 128, 0, stream>>>(A, G, AG, asum);
  k_tokens<<<128, 256, 0, stream>>>(AG, asum, Wu, bu, tokbf);
  k_wprep <<<1024, 256, 0, stream>>>(Wf, Wt, bt, Bt_, wfbf, wtbf, wfbt);
  k_tf1   <<<8, 256, 0, stream>>>(tokbf, wtbf, tfeatbf);
  k_tf2   <<<8, 256, 0, stream>>>(wfbf, tfeatbf, wfbt, Bt_);
  k_cls   <<<8, 256, 0, stream>>>(x, out);
  k_attn  <<<256, 256, 0, stream>>>(x, tokbf, Aext);
  k_main  <<<512, 512, 0, stream>>>(Aext, Bt_, x, bf, scale, out);
}

// Round 4
// 533.875 us; speedup vs baseline: 1.0157x; 1.0157x over previous
//
#include <hip/hip_runtime.h>
#include <stdint.h>

#define EMBED 1024
#define TOKLEN 100
#define TOKDIM 256
#define MLPD 128
#define KEXT 1152   // 1024 body + 128 attn (100 real + 28 zero)

typedef float f32x4 __attribute__((ext_vector_type(4)));
typedef __bf16 bf16x8 __attribute__((ext_vector_type(8)));

__device__ __forceinline__ unsigned short f2bf(float f) {
  unsigned int u = __float_as_uint(f);
  u += 0x7fffu + ((u >> 16) & 1);   // RNE
  return (unsigned short)(u >> 16);
}
__device__ __forceinline__ float bf2f(unsigned short h) {
  return __uint_as_float(((unsigned int)h) << 16);
}
__device__ __forceinline__ void async16(const void* g, void* l) {
  __builtin_amdgcn_global_load_lds(
      (const __attribute__((address_space(1))) unsigned int*)g,
      (__attribute__((address_space(3))) unsigned int*)l, 16, 0, 0);
}

// T2 LDS XOR-swizzle: pre-swizzled SOURCE chunk (schunk^srow) for the linear
// global_load_lds write; same involution ((ks*4+quad)^(row&7)) on ds_read.
// R1 verified: bank conflicts 2.83e7 -> 0.
// R4: k_main fragment-reuse phases — 24 ds_read_b128 per wave per K-tile
// (was 48): B frags held in registers across the tile, A frags read once per
// M-half. LDS-read/CU/tile 384KB -> 192KB ~= MFMA 2064cyc (balance).

// ---------------- small precompute chain ----------------

__global__ void k_gelu(const float* __restrict__ B, const int* __restrict__ layer,
                       const float* __restrict__ Wd, const float* __restrict__ bd,
                       float* __restrict__ G) {
  int idx = blockIdx.x * 256 + threadIdx.x;      // 0..131071
  int c = idx >> 7, j = idx & 127;
  const float* bl = B + ((size_t)layer[0] * EMBED + c) * TOKDIM;
  const float* wd = Wd + (size_t)j * TOKDIM;
  float a0 = 0.f, a1 = 0.f, a2 = 0.f, a3 = 0.f;
  for (int k = 0; k < TOKDIM; k += 4) {
    float4 a = *(const float4*)(bl + k);
    float4 b = *(const float4*)(wd + k);
    a0 += a.x * b.x; a1 += a.y * b.y; a2 += a.z * b.z; a3 += a.w * b.w;
  }
  float v = a0 + a1 + a2 + a3 + bd[j];
  G[idx] = 0.5f * v * (1.f + erff(v * 0.70710678118654752440f));
}

__global__ void k_ag(const float* __restrict__ A, const float* __restrict__ G,
                     float* __restrict__ AG, float* __restrict__ asum) {
  int m = blockIdx.x, j = threadIdx.x;           // 100 blocks x 128 thr
  const float* a = A + (size_t)m * EMBED;
  float acc = 0.f, s = 0.f;
  for (int c = 0; c < EMBED; ++c) acc += a[c] * G[(size_t)c * MLPD + j];
  AG[(size_t)m * MLPD + j] = acc;
  for (int c = j; c < EMBED; c += 128) s += a[c];
  __shared__ float red[128];
  red[j] = s; __syncthreads();
  for (int w = 64; w > 0; w >>= 1) { if (j < w) red[j] += red[j + w]; __syncthreads(); }
  if (j == 0) asum[m] = red[0];
}

__global__ void k_tokens(const float* __restrict__ AG, const float* __restrict__ asum,
                         const float* __restrict__ Wu, const float* __restrict__ bu,
                         unsigned short* __restrict__ tokbf) {
  int m = blockIdx.x, t = threadIdx.x;           // 128 blocks x 256 thr
  if (m >= TOKLEN) {
    #pragma unroll
    for (int i = 0; i < 4; ++i) tokbf[(size_t)m * EMBED + t * 4 + i] = 0;
    return;
  }
  __shared__ float ag[MLPD];
  __shared__ float as_s;
  if (t < MLPD) ag[t] = AG[(size_t)m * MLPD + t];
  if (t == 0) as_s = asum[m];
  __syncthreads();
  #pragma unroll
  for (int i = 0; i < 4; ++i) {
    int e = t * 4 + i;
    const float* wu = Wu + (size_t)e * MLPD;
    float a0 = 0.f, a1 = 0.f, a2 = 0.f, a3 = 0.f;
    for (int j = 0; j < MLPD; j += 4) {
      float4 w = *(const float4*)(wu + j);
      a0 += w.x * ag[j]; a1 += w.y * ag[j + 1]; a2 += w.z * ag[j + 2]; a3 += w.w * ag[j + 3];
    }
    tokbf[(size_t)m * EMBED + e] = f2bf(a0 + a1 + a2 + a3 + as_s * bu[e]);
  }
}

// Fused Wf/Wt precompute
__global__ void k_wprep(const float* __restrict__ Wf, const float* __restrict__ Wt,
                        const float* __restrict__ bt,
                        unsigned short* __restrict__ Bt, unsigned short* __restrict__ wfbf,
                        unsigned short* __restrict__ wtbf, float* __restrict__ wfbt) {
  int e = blockIdx.x, t = threadIdx.x;           // 1024 blocks x 256 thr
  float4 v = *(const float4*)(Wf + (size_t)e * EMBED + t * 4);
  uint2 u;
  u.x = (unsigned int)f2bf(v.x) | ((unsigned int)f2bf(v.y) << 16);
  u.y = (unsigned int)f2bf(v.z) | ((unsigned int)f2bf(v.w) << 16);
  *(uint2*)(Bt + (size_t)e * KEXT + t * 4) = u;
  *(uint2*)(wfbf + (size_t)e * EMBED + t * 4) = u;
  if (t < 28) Bt[(size_t)e * KEXT + 1124 + t] = 0;
  float4 w = *(const float4*)(Wt + (size_t)e * EMBED + t * 4);
  uint2 u2;
  u2.x = (unsigned int)f2bf(w.x) | ((unsigned int)f2bf(w.y) << 16);
  u2.y = (unsigned int)f2bf(w.z) | ((unsigned int)f2bf(w.w) << 16);
  *(uint2*)(wtbf + (size_t)e * EMBED + t * 4) = u2;
  float4 b = *(const float4*)(bt + t * 4);
  __shared__ float red[256];
  red[t] = v.x * b.x + v.y * b.y + v.z * b.z + v.w * b.w;
  __syncthreads();
  for (int s = 128; s > 0; s >>= 1) { if (t < s) red[t] += red[t + s]; __syncthreads(); }
  if (t == 0) wfbt[e] = red[0];
}

__global__ void k_cls(const float* __restrict__ x, float* __restrict__ out) {
  int i = blockIdx.x * 256 + threadIdx.x;        // 8 blocks: 8192 floats
  ((float4*)out)[i] = ((const float4*)x)[i];
}

// ---------------- tfeat path: two MFMA GEMMs (2-phase dbuf) ----------------

__global__ void __launch_bounds__(256) k_tf1(const unsigned short* __restrict__ tokbf,
                                             const unsigned short* __restrict__ wtbf,
                                             unsigned short* __restrict__ tfeatbf) {
  __shared__ unsigned short As[2][128 * 64];
  __shared__ unsigned short Bs[2][128 * 64];
  const int tid = threadIdx.x;
  const int wave = tid >> 6, lane = tid & 63;
  const int l15 = lane & 15, quad = lane >> 4;
  const int srow = lane >> 3, schunk = lane & 7;
  const int col0 = blockIdx.x * 128;
  const int wr = (wave >> 1) * 64, wc = (wave & 1) * 64;

  f32x4 acc[4][4];
  const f32x4 zero = {0.f, 0.f, 0.f, 0.f};
  #pragma unroll
  for (int i = 0; i < 4; ++i)
    #pragma unroll
    for (int j = 0; j < 4; ++j) acc[i][j] = zero;

  auto stage = [&](int buf, int kt) {
    const int k0 = kt * 64;
    #pragma unroll
    for (int i = 0; i < 4; ++i) {
      const int r = i * 32 + wave * 8;
      async16(tokbf + (size_t)(r + srow) * EMBED + k0 + (schunk ^ srow) * 8, &As[buf][r * 64]);
      async16(wtbf + (size_t)(col0 + r + srow) * EMBED + k0 + (schunk ^ srow) * 8, &Bs[buf][r * 64]);
    }
  };
  auto compute = [&](int buf) {
    #pragma unroll
    for (int ks = 0; ks < 2; ++ks) {
      const int sw = ((ks * 4 + quad) ^ (l15 & 7)) * 8;
      bf16x8 a[4], b[4];
      #pragma unroll
      for (int i = 0; i < 4; ++i)
        a[i] = *(const bf16x8*)&As[buf][(wr + i * 16 + l15) * 64 + sw];
      #pragma unroll
      for (int j = 0; j < 4; ++j)
        b[j] = *(const bf16x8*)&Bs[buf][(wc + j * 16 + l15) * 64 + sw];
      #pragma unroll
      for (int i = 0; i < 4; ++i)
        #pragma unroll
        for (int j = 0; j < 4; ++j)
          acc[i][j] = __builtin_amdgcn_mfma_f32_16x16x32_bf16(a[i], b[j], acc[i][j], 0, 0, 0);
    }
  };

  stage(0, 0);
  asm volatile("s_waitcnt vmcnt(0)" ::: "memory");
  __syncthreads();
  int cur = 0;
  for (int kt = 0; kt < 16; ++kt) {
    if (kt < 15) stage(cur ^ 1, kt + 1);
    compute(cur);
    asm volatile("s_waitcnt vmcnt(0)" ::: "memory");
    __syncthreads();
    cur ^= 1;
  }
  #pragma unroll
  for (int j = 0; j < 4; ++j) {
    const int e = col0 + wc + j * 16 + l15;
    #pragma unroll
    for (int i = 0; i < 4; ++i) {
      const int mb = wr + i * 16 + quad * 4;
      #pragma unroll
      for (int r = 0; r < 4; ++r)
        tfeatbf[(size_t)(mb + r) * EMBED + e] = f2bf(acc[i][j][r]);
    }
  }
}

__global__ void __launch_bounds__(256) k_tf2(const unsigned short* __restrict__ wfbf,
                                             const unsigned short* __restrict__ tfeatbf,
                                             const float* __restrict__ wfbt,
                                             unsigned short* __restrict__ Bt) {
  __shared__ unsigned short As[2][128 * 64];
  __shared__ unsigned short Bs[2][128 * 64];
  const int tid = threadIdx.x;
  const int wave = tid >> 6, lane = tid & 63;
  const int l15 = lane & 15, quad = lane >> 4;
  const int srow = lane >> 3, schunk = lane & 7;
  const int row0 = blockIdx.x * 128;
  const int wr = (wave >> 1) * 64, wc = (wave & 1) * 64;

  f32x4 acc[4][4];
  const f32x4 zero = {0.f, 0.f, 0.f, 0.f};
  #pragma unroll
  for (int i = 0; i < 4; ++i)
    #pragma unroll
    for (int j = 0; j < 4; ++j) acc[i][j] = zero;

  auto stage = [&](int buf, int kt) {
    const int k0 = kt * 64;
    #pragma unroll
    for (int i = 0; i < 4; ++i) {
      const int r = i * 32 + wave * 8;
      async16(wfbf + (size_t)(row0 + r + srow) * EMBED + k0 + (schunk ^ srow) * 8, &As[buf][r * 64]);
      async16(tfeatbf + (size_t)(r + srow) * EMBED + k0 + (schunk ^ srow) * 8, &Bs[buf][r * 64]);
    }
  };
  auto compute = [&](int buf) {
    #pragma unroll
    for (int ks = 0; ks < 2; ++ks) {
      const int sw = ((ks * 4 + quad) ^ (l15 & 7)) * 8;
      bf16x8 a[4], b[4];
      #pragma unroll
      for (int i = 0; i < 4; ++i)
        a[i] = *(const bf16x8*)&As[buf][(wr + i * 16 + l15) * 64 + sw];
      #pragma unroll
      for (int j = 0; j < 4; ++j)
        b[j] = *(const bf16x8*)&Bs[buf][(wc + j * 16 + l15) * 64 + sw];
      #pragma unroll
      for (int i = 0; i < 4; ++i)
        #pragma unroll
        for (int j = 0; j < 4; ++j)
          acc[i][j] = __builtin_amdgcn_mfma_f32_16x16x32_bf16(a[i], b[j], acc[i][j], 0, 0, 0);
    }
  };

  stage(0, 0);
  asm volatile("s_waitcnt vmcnt(0)" ::: "memory");
  __syncthreads();
  int cur = 0;
  for (int kt = 0; kt < 16; ++kt) {
    if (kt < 15) stage(cur ^ 1, kt + 1);
    compute(cur);
    asm volatile("s_waitcnt vmcnt(0)" ::: "memory");
    __syncthreads();
    cur ^= 1;
  }
  #pragma unroll
  for (int j = 0; j < 4; ++j) {
    const int m = wc + j * 16 + l15;
    #pragma unroll
    for (int i = 0; i < 4; ++i) {
      const int eb = row0 + wr + i * 16 + quad * 4;
      #pragma unroll
      for (int r = 0; r < 4; ++r)
        Bt[(size_t)(eb + r) * KEXT + 1024 + m] = f2bf(acc[i][j][r] + wfbt[eb + r]);
    }
  }
}

// ---------------- attention scores + softmax -> A_ext ----------------
__global__ void __launch_bounds__(256) k_attn(const float* __restrict__ x,
                                              const unsigned short* __restrict__ tokbf,
                                              unsigned short* __restrict__ Aext) {
  __shared__ __align__(16) unsigned short smem[2 * 128 * 72 + 2 * 128 * 64];
  const int tid = threadIdx.x;
  const int wave = tid >> 6, lane = tid & 63;
  const int l15 = lane & 15, quad = lane >> 4;
  const int srow = lane >> 3, schunk = lane & 7;
  const int row0 = blockIdx.x * 128;
  const int trow = tid >> 1, thalf = tid & 1;
  const float* body = x + 8 * EMBED;
  const float* gxbase = body + (size_t)(row0 + trow) * EMBED + thalf * 32;

  f32x4 acc[2][8];
  const f32x4 zero = {0.f, 0.f, 0.f, 0.f};
  #pragma unroll
  for (int i = 0; i < 2; ++i)
    #pragma unroll
    for (int j = 0; j < 8; ++j) acc[i][j] = zero;

  float4 v[8];

  auto regload = [&](int kt) {
    const float* gx = gxbase + kt * 64;
    #pragma unroll
    for (int q = 0; q < 8; ++q) v[q] = *(const float4*)(gx + q * 4);
  };
  auto tsstage = [&](int buf, int kt) {
    unsigned short* Ts = smem + 2 * 128 * 72 + buf * (128 * 64);
    const int k0 = kt * 64;
    #pragma unroll
    for (int i = 0; i < 4; ++i) {
      const int r = i * 32 + wave * 8;
      async16(tokbf + (size_t)(r + srow) * EMBED + k0 + (schunk ^ srow) * 8, &Ts[r * 64]);
    }
  };
  auto convwrite = [&](int buf, int kt) {
    unsigned short* As = smem + buf * (128 * 72);
    unsigned int pk[16];
    #pragma unroll
    for (int q = 0; q < 8; ++q) {
      pk[q * 2]     = (unsigned int)f2bf(v[q].x) | ((unsigned int)f2bf(v[q].y) << 16);
      pk[q * 2 + 1] = (unsigned int)f2bf(v[q].z) | ((unsigned int)f2bf(v[q].w) << 16);
    }
    unsigned int* lw = (unsigned int*)&As[trow * 72 + thalf * 32];
    unsigned int* gw = (unsigned int*)(Aext + (size_t)(row0 + trow) * KEXT + kt * 64 + thalf * 32);
    #pragma unroll
    for (int q = 0; q < 4; ++q) {
      uint4 u; u.x = pk[q*4]; u.y = pk[q*4+1]; u.z = pk[q*4+2]; u.w = pk[q*4+3];
      ((uint4*)lw)[q] = u;
      ((uint4*)gw)[q] = u;
    }
  };
  auto compute = [&](int buf) {
    unsigned short* As = smem + buf * (128 * 72);
    unsigned short* Ts = smem + 2 * 128 * 72 + buf * (128 * 64);
    #pragma unroll
    for (int ks = 0; ks < 2; ++ks) {
      const int sw = ((ks * 4 + quad) ^ (l15 & 7)) * 8;
      bf16x8 a[2], b[8];
      #pragma unroll
      for (int i = 0; i < 2; ++i)
        a[i] = *(const bf16x8*)&As[(wave * 32 + i * 16 + l15) * 72 + ks * 32 + quad * 8];
      #pragma unroll
      for (int j = 0; j < 8; ++j)
        b[j] = *(const bf16x8*)&Ts[(j * 16 + l15) * 64 + sw];
      #pragma unroll
      for (int i = 0; i < 2; ++i)
        #pragma unroll
        for (int j = 0; j < 8; ++j)
          acc[i][j] = __builtin_amdgcn_mfma_f32_16x16x32_bf16(a[i], b[j], acc[i][j], 0, 0, 0);
    }
  };

  regload(0); tsstage(0, 0);
  asm volatile("s_waitcnt vmcnt(0)" ::: "memory");
  convwrite(0, 0);
  __syncthreads();
  int cur = 0;
  for (int kt = 0; kt < 16; ++kt) {
    if (kt < 15) { regload(kt + 1); tsstage(cur ^ 1, kt + 1); }
    compute(cur);
    if (kt < 15) {
      asm volatile("s_waitcnt vmcnt(0)" ::: "memory");
      convwrite(cur ^ 1, kt + 1);
    }
    __syncthreads();
    cur ^= 1;
  }

  unsigned short* Sc = smem;
  #pragma unroll
  for (int i = 0; i < 2; ++i) {
    #pragma unroll
    for (int r = 0; r < 4; ++r) {
      float mx = -1e30f;
      #pragma unroll
      for (int j = 0; j < 8; ++j) {
        const int c = j * 16 + l15;
        const float vv = acc[i][j][r] * 0.03125f;
        if (c < TOKLEN) mx = fmaxf(mx, vv);
      }
      #pragma unroll
      for (int d = 1; d < 16; d <<= 1) mx = fmaxf(mx, __shfl_xor(mx, d));
      float sm = 0.f;
      #pragma unroll
      for (int j = 0; j < 8; ++j) {
        const int c = j * 16 + l15;
        if (c < TOKLEN) sm += __expf(acc[i][j][r] * 0.03125f - mx);
      }
      #pragma unroll
      for (int d = 1; d < 16; d <<= 1) sm += __shfl_xor(sm, d);
      const float inv = 1.f / sm;
      const int row = wave * 32 + i * 16 + quad * 4 + r;
      #pragma unroll
      for (int j = 0; j < 8; ++j) {
        const int c = j * 16 + l15;
        const float p = (c < TOKLEN) ? __expf(acc[i][j][r] * 0.03125f - mx) * inv : 0.f;
        Sc[row * 128 + c] = f2bf(p);
      }
    }
  }
  __syncthreads();
  {
    const int r = tid >> 1, h = tid & 1;
    const uint4* src = (const uint4*)(Sc + r * 128 + h * 64);
    uint4* dst = (uint4*)(Aext + (size_t)(row0 + r) * KEXT + 1024 + h * 64);
    dst[0] = src[0]; dst[1] = src[1]; dst[2] = src[2]; dst[3] = src[3];
  }
}

// ---------------- main GEMM: 256x256 tile, fragment-reuse phases ----------
// C = A_ext(32768x1152) @ Bt(1024x1152)^T. Grid 512 = 128 rowtiles x 4
// coltiles, XCD-aware. 512 thr = 8 waves (2M x 4N), per-wave C = 128x64.
// LDS 128KB: 2 sets x {A 2x(128x64), B 2x(128x64)}.
// Per K-tile (set S): 2 phases.
//   phase0: read 8 B-frags (held in regs across tile) + 8 A-frags (MH=0),
//           barrier, setprio(1), 32 MFMA, setprio(0), barrier.
//   phase1: read 8 A-frags (MH=1), reuse B regs, 32 MFMA.
// 24 ds_read_b128 / wave / K-tile (was 48) -> LDS-read/CU/tile 192KB
// (~2300cyc) ~= MFMA (2064cyc). Raw s_barrier keeps staging loads in
// flight; vmcnt(0)+barrier only at tile boundaries.

#define MAIN_MFMA16(MH, KS)                                                     \
    acc[(MH)*4+0][0] = __builtin_amdgcn_mfma_f32_16x16x32_bf16(pa0##KS, pb0##KS, acc[(MH)*4+0][0], 0, 0, 0); \
    acc[(MH)*4+1][0] = __builtin_amdgcn_mfma_f32_16x16x32_bf16(pa1##KS, pb0##KS, acc[(MH)*4+1][0], 0, 0, 0); \
    acc[(MH)*4+2][0] = __builtin_amdgcn_mfma_f32_16x16x32_bf16(pa2##KS, pb0##KS, acc[(MH)*4+2][0], 0, 0, 0); \
    acc[(MH)*4+3][0] = __builtin_amdgcn_mfma_f32_16x16x32_bf16(pa3##KS, pb0##KS, acc[(MH)*4+3][0], 0, 0, 0); \
    acc[(MH)*4+0][1] = __builtin_amdgcn_mfma_f32_16x16x32_bf16(pa0##KS, pb1##KS, acc[(MH)*4+0][1], 0, 0, 0); \
    acc[(MH)*4+1][1] = __builtin_amdgcn_mfma_f32_16x16x32_bf16(pa1##KS, pb1##KS, acc[(MH)*4+1][1], 0, 0, 0); \
    acc[(MH)*4+2][1] = __builtin_amdgcn_mfma_f32_16x16x32_bf16(pa2##KS, pb1##KS, acc[(MH)*4+2][1], 0, 0, 0); \
    acc[(MH)*4+3][1] = __builtin_amdgcn_mfma_f32_16x16x32_bf16(pa3##KS, pb1##KS, acc[(MH)*4+3][1], 0, 0, 0); \
    acc[(MH)*4+0][2] = __builtin_amdgcn_mfma_f32_16x16x32_bf16(pa0##KS, pb2##KS, acc[(MH)*4+0][2], 0, 0, 0); \
    acc[(MH)*4+1][2] = __builtin_amdgcn_mfma_f32_16x16x32_bf16(pa1##KS, pb2##KS, acc[(MH)*4+1][2], 0, 0, 0); \
    acc[(MH)*4+2][2] = __builtin_amdgcn_mfma_f32_16x16x32_bf16(pa2##KS, pb2##KS, acc[(MH)*4+2][2], 0, 0, 0); \
    acc[(MH)*4+3][2] = __builtin_amdgcn_mfma_f32_16x16x32_bf16(pa3##KS, pb2##KS, acc[(MH)*4+3][2], 0, 0, 0); \
    acc[(MH)*4+0][3] = __builtin_amdgcn_mfma_f32_16x16x32_bf16(pa0##KS, pb3##KS, acc[(MH)*4+0][3], 0, 0, 0); \
    acc[(MH)*4+1][3] = __builtin_amdgcn_mfma_f32_16x16x32_bf16(pa1##KS, pb3##KS, acc[(MH)*4+1][3], 0, 0, 0); \
    acc[(MH)*4+2][3] = __builtin_amdgcn_mfma_f32_16x16x32_bf16(pa2##KS, pb3##KS, acc[(MH)*4+2][3], 0, 0, 0); \
    acc[(MH)*4+3][3] = __builtin_amdgcn_mfma_f32_16x16x32_bf16(pa3##KS, pb3##KS, acc[(MH)*4+3][3], 0, 0, 0);

#define MAIN_PHASE(S, MH, LOADB)                                                \
  do {                                                                          \
    const int sw0 = (quad ^ (l15 & 7)) * 8;                                     \
    const int sw1 = ((4 + quad) ^ (l15 & 7)) * 8;                               \
    const unsigned short* Ah = &Ab[S][wm][0];                                   \
    if (LOADB) {                                                                \
      const unsigned short* Bh = &Bb[S][bh][0];                                 \
      pb0_0 = *(const bf16x8*)&Bh[(brb + 0 * 16 + l15) * 64 + sw0];             \
      pb1_0 = *(const bf16x8*)&Bh[(brb + 1 * 16 + l15) * 64 + sw0];             \
      pb2_0 = *(const bf16x8*)&Bh[(brb + 2 * 16 + l15) * 64 + sw0];             \
      pb3_0 = *(const bf16x8*)&Bh[(brb + 3 * 16 + l15) * 64 + sw0];             \
      pb0_1 = *(const bf16x8*)&Bh[(brb + 0 * 16 + l15) * 64 + sw1];             \
      pb1_1 = *(const bf16x8*)&Bh[(brb + 1 * 16 + l15) * 64 + sw1];             \
      pb2_1 = *(const bf16x8*)&Bh[(brb + 2 * 16 + l15) * 64 + sw1];             \
      pb3_1 = *(const bf16x8*)&Bh[(brb + 3 * 16 + l15) * 64 + sw1];             \
    }                                                                           \
    bf16x8 pa0_0 = *(const bf16x8*)&Ah[((MH)*64 + 0 * 16 + l15) * 64 + sw0];    \
    bf16x8 pa1_0 = *(const bf16x8*)&Ah[((MH)*64 + 1 * 16 + l15) * 64 + sw0];    \
    bf16x8 pa2_0 = *(const bf16x8*)&Ah[((MH)*64 + 2 * 16 + l15) * 64 + sw0];    \
    bf16x8 pa3_0 = *(const bf16x8*)&Ah[((MH)*64 + 3 * 16 + l15) * 64 + sw0];    \
    bf16x8 pa0_1 = *(const bf16x8*)&Ah[((MH)*64 + 0 * 16 + l15) * 64 + sw1];    \
    bf16x8 pa1_1 = *(const bf16x8*)&Ah[((MH)*64 + 1 * 16 + l15) * 64 + sw1];    \
    bf16x8 pa2_1 = *(const bf16x8*)&Ah[((MH)*64 + 2 * 16 + l15) * 64 + sw1];    \
    bf16x8 pa3_1 = *(const bf16x8*)&Ah[((MH)*64 + 3 * 16 + l15) * 64 + sw1];    \
    asm volatile("s_barrier" ::: "memory");                                     \
    __builtin_amdgcn_s_setprio(1);                                              \
    MAIN_MFMA16(MH, _0)                                                         \
    MAIN_MFMA16(MH, _1)                                                         \
    __builtin_amdgcn_s_setprio(0);                                              \
    asm volatile("s_barrier" ::: "memory");                                     \
  } while (0)

#define ISSUE_TILE(KT, S)                                                       \
  do {                                                                          \
    const int k0_ = (KT) * 64;                                                  \
    _Pragma("unroll")                                                           \
    for (int h_ = 0; h_ < 2; ++h_) {                                            \
      _Pragma("unroll")                                                         \
      for (int r2_ = 0; r2_ < 2; ++r2_) {                                       \
        const int rb_ = r2_ * 64 + w8;                                          \
        async16(Aext + (size_t)(row0 + h_ * 128 + rb_ + srow) * KEXT + k0_ + (schunk ^ srow) * 8, \
                &Ab[S][h_][rb_ * 64]);                                          \
        async16(Bt + (size_t)(col0 + h_ * 128 + rb_ + srow) * KEXT + k0_ + (schunk ^ srow) * 8,   \
                &Bb[S][h_][rb_ * 64]);                                          \
      }                                                                         \
    }                                                                           \
  } while (0)

__global__ void __launch_bounds__(512) k_main(const unsigned short* __restrict__ Aext,
                                              const unsigned short* __restrict__ Bt,
                                              const float* __restrict__ x,
                                              const float* __restrict__ bfv,
                                              const float* __restrict__ scale,
                                              float* __restrict__ out) {
  __shared__ unsigned short Ab[2][2][128 * 64];   // [set][M-half][row*64+chunk]
  __shared__ unsigned short Bb[2][2][128 * 64];   // [set][N-half]
  const int tid = threadIdx.x;
  const int w = tid >> 6, lane = tid & 63;
  const int l15 = lane & 15, quad = lane >> 4;
  const int srow = lane >> 3, schunk = lane & 7;
  const int w8 = w * 8;
  const int wm = w >> 2, wn = w & 3;
  const int bh = wn >> 1, brb = (wn & 1) * 64;

  const int xcd = blockIdx.x & 7, slot = blockIdx.x >> 3;
  const int rt = (slot >> 2) * 8 + xcd;           // 0..127
  const int ct = slot & 3;                        // 0..3
  const int row0 = rt * 256;
  const int col0 = ct * 256;

  f32x4 acc[8][4];
  const f32x4 zero = {0.f, 0.f, 0.f, 0.f};
  #pragma unroll
  for (int i = 0; i < 8; ++i)
    #pragma unroll
    for (int j = 0; j < 4; ++j) acc[i][j] = zero;

  bf16x8 pb0_0, pb1_0, pb2_0, pb3_0, pb0_1, pb1_1, pb2_1, pb3_1;

  ISSUE_TILE(0, 0);
  #pragma unroll 1
  for (int i = 0; i < 9; ++i) {
    // ---- boundary: K-tile 2i (set0) ready ----
    asm volatile("s_waitcnt vmcnt(0)" ::: "memory");
    asm volatile("s_barrier" ::: "memory");
    ISSUE_TILE(2 * i + 1, 1);                     // always <= 17
    MAIN_PHASE(0, 0, 1);
    MAIN_PHASE(0, 1, 0);
    // ---- boundary: K-tile 2i+1 (set1) ready ----
    asm volatile("s_waitcnt vmcnt(0)" ::: "memory");
    asm volatile("s_barrier" ::: "memory");
    if (i < 8) ISSUE_TILE(2 * i + 2, 0);
    MAIN_PHASE(1, 0, 1);
    MAIN_PHASE(1, 1, 0);
  }

  const float s = scale[0];
  #pragma unroll
  for (int mf = 0; mf < 8; ++mf) {
    const int rb = row0 + wm * 128 + mf * 16 + quad * 4;
    #pragma unroll
    for (int nf = 0; nf < 4; ++nf) {
      const int c = col0 + wn * 64 + nf * 16 + l15;
      const float bfc = bfv[c];
      #pragma unroll
      for (int r = 0; r < 4; ++r) {
        const size_t idx = (size_t)(rb + r + 8) * EMBED + c;
        out[idx] = x[idx] + (acc[mf][nf][r] + bfc) * s;
      }
    }
  }
}

extern "C" void kernel_launch(void* const* d_in, const int* in_sizes, int n_in,
                              void* d_out, int out_size, void* d_ws, size_t ws_size,
                              hipStream_t stream) {
  const float* x     = (const float*)d_in[0];
  const int*   layer = (const int*)d_in[1];
  const float* A     = (const float*)d_in[2];
  const float* B     = (const float*)d_in[3];
  const float* Wd    = (const float*)d_in[4];
  const float* bd    = (const float*)d_in[5];
  const float* Wu    = (const float*)d_in[6];
  const float* bu    = (const float*)d_in[7];
  const float* Wt    = (const float*)d_in[8];
  const float* bt    = (const float*)d_in[9];
  const float* Wf    = (const float*)d_in[10];
  const float* bf    = (const float*)d_in[11];
  const float* scale = (const float*)d_in[12];
  float* out = (float*)d_out;

  char* ws = (char*)d_ws;
  unsigned short* Aext    = (unsigned short*)(ws + 0);          // 32768*1152*2
  unsigned short* wtbf    = (unsigned short*)(ws + 0);          // alias (dead before k_attn)
  unsigned short* wfbf    = (unsigned short*)(ws + 2097152);    // alias
  unsigned short* Bt_     = (unsigned short*)(ws + 75497472);   // 1024*1152*2
  unsigned short* tokbf   = (unsigned short*)(ws + 77856768);   // 128*1024*2
  float*          G       = (float*)(ws + 78118912);            // 1024*128*4
  float*          AG      = (float*)(ws + 78643200);            // 100*128*4
  float*          asum    = (float*)(ws + 78694400);            // 128*4
  float*          wfbt    = (float*)(ws + 78694912);            // 1024*4
  unsigned short* tfeatbf = (unsigned short*)(ws + 78699008);   // 128*1024*2

  k_gelu  <<<512, 256, 0, stream>>>(B, layer, Wd, bd, G);
  k_ag    <<<100, 128, 0, stream>>>(A, G, AG, asum);
  k_tokens<<<128, 256, 0, stream>>>(AG, asum, Wu, bu, tokbf);
  k_wprep <<<1024, 256, 0, stream>>>(Wf, Wt, bt, Bt_, wfbf, wtbf, wfbt);
  k_tf1   <<<8, 256, 0, stream>>>(tokbf, wtbf, tfeatbf);
  k_tf2   <<<8, 256, 0, stream>>>(wfbf, tfeatbf, wfbt, Bt_);
  k_cls   <<<8, 256, 0, stream>>>(x, out);
  k_attn  <<<256, 256, 0, stream>>>(x, tokbf, Aext);
  k_main  <<<512, 512, 0, stream>>>(Aext, Bt_, x, bf, scale, out);
}

// Round 5
// 528.087 us; speedup vs baseline: 1.0268x; 1.0110x over previous
//
#include <hip/hip_runtime.h>
#include <stdint.h>

#define EMBED 1024
#define TOKLEN 100
#define TOKDIM 256
#define MLPD 128
#define KEXT 1152   // 1024 body + 128 attn (100 real + 28 zero)

typedef float f32x4 __attribute__((ext_vector_type(4)));
typedef __bf16 bf16x8 __attribute__((ext_vector_type(8)));

__device__ __forceinline__ unsigned short f2bf(float f) {
  unsigned int u = __float_as_uint(f);
  u += 0x7fffu + ((u >> 16) & 1);   // RNE
  return (unsigned short)(u >> 16);
}
__device__ __forceinline__ float bf2f(unsigned short h) {
  return __uint_as_float(((unsigned int)h) << 16);
}
__device__ __forceinline__ void async16(const void* g, void* l) {
  __builtin_amdgcn_global_load_lds(
      (const __attribute__((address_space(1))) unsigned int*)g,
      (__attribute__((address_space(3))) unsigned int*)l, 16, 0, 0);
}

// T2 LDS XOR-swizzle (R1: conflicts 2.83e7 -> 0).
// R5: T4 counted vmcnt in k_main and k_attn — issue next+1 tile's loads
// BEFORE waiting vmcnt(8) for next tile; the load queue never drains to 0
// in the main loop (m218's isolated lever). Raw s_barrier throughout the
// pipelined loops (never __syncthreads, which drains vmcnt).

// ---------------- small precompute chain ----------------

__global__ void k_gelu(const float* __restrict__ B, const int* __restrict__ layer,
                       const float* __restrict__ Wd, const float* __restrict__ bd,
                       float* __restrict__ G) {
  int idx = blockIdx.x * 256 + threadIdx.x;      // 0..131071
  int c = idx >> 7, j = idx & 127;
  const float* bl = B + ((size_t)layer[0] * EMBED + c) * TOKDIM;
  const float* wd = Wd + (size_t)j * TOKDIM;
  float a0 = 0.f, a1 = 0.f, a2 = 0.f, a3 = 0.f;
  for (int k = 0; k < TOKDIM; k += 4) {
    float4 a = *(const float4*)(bl + k);
    float4 b = *(const float4*)(wd + k);
    a0 += a.x * b.x; a1 += a.y * b.y; a2 += a.z * b.z; a3 += a.w * b.w;
  }
  float v = a0 + a1 + a2 + a3 + bd[j];
  G[idx] = 0.5f * v * (1.f + erff(v * 0.70710678118654752440f));
}

__global__ void k_ag(const float* __restrict__ A, const float* __restrict__ G,
                     float* __restrict__ AG, float* __restrict__ asum) {
  int m = blockIdx.x, j = threadIdx.x;           // 100 blocks x 128 thr
  const float* a = A + (size_t)m * EMBED;
  float acc = 0.f, s = 0.f;
  for (int c = 0; c < EMBED; ++c) acc += a[c] * G[(size_t)c * MLPD + j];
  AG[(size_t)m * MLPD + j] = acc;
  for (int c = j; c < EMBED; c += 128) s += a[c];
  __shared__ float red[128];
  red[j] = s; __syncthreads();
  for (int w = 64; w > 0; w >>= 1) { if (j < w) red[j] += red[j + w]; __syncthreads(); }
  if (j == 0) asum[m] = red[0];
}

__global__ void k_tokens(const float* __restrict__ AG, const float* __restrict__ asum,
                         const float* __restrict__ Wu, const float* __restrict__ bu,
                         unsigned short* __restrict__ tokbf) {
  int m = blockIdx.x, t = threadIdx.x;           // 128 blocks x 256 thr
  if (m >= TOKLEN) {
    #pragma unroll
    for (int i = 0; i < 4; ++i) tokbf[(size_t)m * EMBED + t * 4 + i] = 0;
    return;
  }
  __shared__ float ag[MLPD];
  __shared__ float as_s;
  if (t < MLPD) ag[t] = AG[(size_t)m * MLPD + t];
  if (t == 0) as_s = asum[m];
  __syncthreads();
  #pragma unroll
  for (int i = 0; i < 4; ++i) {
    int e = t * 4 + i;
    const float* wu = Wu + (size_t)e * MLPD;
    float a0 = 0.f, a1 = 0.f, a2 = 0.f, a3 = 0.f;
    for (int j = 0; j < MLPD; j += 4) {
      float4 w = *(const float4*)(wu + j);
      a0 += w.x * ag[j]; a1 += w.y * ag[j + 1]; a2 += w.z * ag[j + 2]; a3 += w.w * ag[j + 3];
    }
    tokbf[(size_t)m * EMBED + e] = f2bf(a0 + a1 + a2 + a3 + as_s * bu[e]);
  }
}

// Fused Wf/Wt precompute + cls copy (k_cls merged: blocks 0-7 copy x[0:8192])
__global__ void k_wprep(const float* __restrict__ Wf, const float* __restrict__ Wt,
                        const float* __restrict__ bt, const float* __restrict__ x,
                        float* __restrict__ out,
                        unsigned short* __restrict__ Bt, unsigned short* __restrict__ wfbf,
                        unsigned short* __restrict__ wtbf, float* __restrict__ wfbt) {
  int e = blockIdx.x, t = threadIdx.x;           // 1024 blocks x 256 thr
  if (e < 8) {
    int i = e * 256 + t;
    ((float4*)out)[i] = ((const float4*)x)[i];
  }
  float4 v = *(const float4*)(Wf + (size_t)e * EMBED + t * 4);
  uint2 u;
  u.x = (unsigned int)f2bf(v.x) | ((unsigned int)f2bf(v.y) << 16);
  u.y = (unsigned int)f2bf(v.z) | ((unsigned int)f2bf(v.w) << 16);
  *(uint2*)(Bt + (size_t)e * KEXT + t * 4) = u;
  *(uint2*)(wfbf + (size_t)e * EMBED + t * 4) = u;
  if (t < 28) Bt[(size_t)e * KEXT + 1124 + t] = 0;
  float4 w = *(const float4*)(Wt + (size_t)e * EMBED + t * 4);
  uint2 u2;
  u2.x = (unsigned int)f2bf(w.x) | ((unsigned int)f2bf(w.y) << 16);
  u2.y = (unsigned int)f2bf(w.z) | ((unsigned int)f2bf(w.w) << 16);
  *(uint2*)(wtbf + (size_t)e * EMBED + t * 4) = u2;
  float4 b = *(const float4*)(bt + t * 4);
  __shared__ float red[256];
  red[t] = v.x * b.x + v.y * b.y + v.z * b.z + v.w * b.w;
  __syncthreads();
  for (int s = 128; s > 0; s >>= 1) { if (t < s) red[t] += red[t + s]; __syncthreads(); }
  if (t == 0) wfbt[e] = red[0];
}

// ---------------- tfeat path: two MFMA GEMMs (2-phase dbuf) ----------------

__global__ void __launch_bounds__(256) k_tf1(const unsigned short* __restrict__ tokbf,
                                             const unsigned short* __restrict__ wtbf,
                                             unsigned short* __restrict__ tfeatbf) {
  __shared__ unsigned short As[2][128 * 64];
  __shared__ unsigned short Bs[2][128 * 64];
  const int tid = threadIdx.x;
  const int wave = tid >> 6, lane = tid & 63;
  const int l15 = lane & 15, quad = lane >> 4;
  const int srow = lane >> 3, schunk = lane & 7;
  const int col0 = blockIdx.x * 128;
  const int wr = (wave >> 1) * 64, wc = (wave & 1) * 64;

  f32x4 acc[4][4];
  const f32x4 zero = {0.f, 0.f, 0.f, 0.f};
  #pragma unroll
  for (int i = 0; i < 4; ++i)
    #pragma unroll
    for (int j = 0; j < 4; ++j) acc[i][j] = zero;

  auto stage = [&](int buf, int kt) {
    const int k0 = kt * 64;
    #pragma unroll
    for (int i = 0; i < 4; ++i) {
      const int r = i * 32 + wave * 8;
      async16(tokbf + (size_t)(r + srow) * EMBED + k0 + (schunk ^ srow) * 8, &As[buf][r * 64]);
      async16(wtbf + (size_t)(col0 + r + srow) * EMBED + k0 + (schunk ^ srow) * 8, &Bs[buf][r * 64]);
    }
  };
  auto compute = [&](int buf) {
    #pragma unroll
    for (int ks = 0; ks < 2; ++ks) {
      const int sw = ((ks * 4 + quad) ^ (l15 & 7)) * 8;
      bf16x8 a[4], b[4];
      #pragma unroll
      for (int i = 0; i < 4; ++i)
        a[i] = *(const bf16x8*)&As[buf][(wr + i * 16 + l15) * 64 + sw];
      #pragma unroll
      for (int j = 0; j < 4; ++j)
        b[j] = *(const bf16x8*)&Bs[buf][(wc + j * 16 + l15) * 64 + sw];
      #pragma unroll
      for (int i = 0; i < 4; ++i)
        #pragma unroll
        for (int j = 0; j < 4; ++j)
          acc[i][j] = __builtin_amdgcn_mfma_f32_16x16x32_bf16(a[i], b[j], acc[i][j], 0, 0, 0);
    }
  };

  stage(0, 0);
  asm volatile("s_waitcnt vmcnt(0)" ::: "memory");
  __syncthreads();
  int cur = 0;
  for (int kt = 0; kt < 16; ++kt) {
    if (kt < 15) stage(cur ^ 1, kt + 1);
    compute(cur);
    asm volatile("s_waitcnt vmcnt(0)" ::: "memory");
    __syncthreads();
    cur ^= 1;
  }
  #pragma unroll
  for (int j = 0; j < 4; ++j) {
    const int e = col0 + wc + j * 16 + l15;
    #pragma unroll
    for (int i = 0; i < 4; ++i) {
      const int mb = wr + i * 16 + quad * 4;
      #pragma unroll
      for (int r = 0; r < 4; ++r)
        tfeatbf[(size_t)(mb + r) * EMBED + e] = f2bf(acc[i][j][r]);
    }
  }
}

__global__ void __launch_bounds__(256) k_tf2(const unsigned short* __restrict__ wfbf,
                                             const unsigned short* __restrict__ tfeatbf,
                                             const float* __restrict__ wfbt,
                                             unsigned short* __restrict__ Bt) {
  __shared__ unsigned short As[2][128 * 64];
  __shared__ unsigned short Bs[2][128 * 64];
  const int tid = threadIdx.x;
  const int wave = tid >> 6, lane = tid & 63;
  const int l15 = lane & 15, quad = lane >> 4;
  const int srow = lane >> 3, schunk = lane & 7;
  const int row0 = blockIdx.x * 128;
  const int wr = (wave >> 1) * 64, wc = (wave & 1) * 64;

  f32x4 acc[4][4];
  const f32x4 zero = {0.f, 0.f, 0.f, 0.f};
  #pragma unroll
  for (int i = 0; i < 4; ++i)
    #pragma unroll
    for (int j = 0; j < 4; ++j) acc[i][j] = zero;

  auto stage = [&](int buf, int kt) {
    const int k0 = kt * 64;
    #pragma unroll
    for (int i = 0; i < 4; ++i) {
      const int r = i * 32 + wave * 8;
      async16(wfbf + (size_t)(row0 + r + srow) * EMBED + k0 + (schunk ^ srow) * 8, &As[buf][r * 64]);
      async16(tfeatbf + (size_t)(r + srow) * EMBED + k0 + (schunk ^ srow) * 8, &Bs[buf][r * 64]);
    }
  };
  auto compute = [&](int buf) {
    #pragma unroll
    for (int ks = 0; ks < 2; ++ks) {
      const int sw = ((ks * 4 + quad) ^ (l15 & 7)) * 8;
      bf16x8 a[4], b[4];
      #pragma unroll
      for (int i = 0; i < 4; ++i)
        a[i] = *(const bf16x8*)&As[buf][(wr + i * 16 + l15) * 64 + sw];
      #pragma unroll
      for (int j = 0; j < 4; ++j)
        b[j] = *(const bf16x8*)&Bs[buf][(wc + j * 16 + l15) * 64 + sw];
      #pragma unroll
      for (int i = 0; i < 4; ++i)
        #pragma unroll
        for (int j = 0; j < 4; ++j)
          acc[i][j] = __builtin_amdgcn_mfma_f32_16x16x32_bf16(a[i], b[j], acc[i][j], 0, 0, 0);
    }
  };

  stage(0, 0);
  asm volatile("s_waitcnt vmcnt(0)" ::: "memory");
  __syncthreads();
  int cur = 0;
  for (int kt = 0; kt < 16; ++kt) {
    if (kt < 15) stage(cur ^ 1, kt + 1);
    compute(cur);
    asm volatile("s_waitcnt vmcnt(0)" ::: "memory");
    __syncthreads();
    cur ^= 1;
  }
  #pragma unroll
  for (int j = 0; j < 4; ++j) {
    const int m = wc + j * 16 + l15;
    #pragma unroll
    for (int i = 0; i < 4; ++i) {
      const int eb = row0 + wr + i * 16 + quad * 4;
      #pragma unroll
      for (int r = 0; r < 4; ++r)
        Bt[(size_t)(eb + r) * KEXT + 1024 + m] = f2bf(acc[i][j][r] + wfbt[eb + r]);
    }
  }
}

// ---------------- attention scores + softmax -> A_ext ----------------
// R5: raw-barrier pipeline with counted vmcnt. Per iteration kt:
//   A: tsstage(kt+1 -> Ts[cur^1])    (4 gload_lds; safe: barrier passed)
//   B: regload(kt+2 -> v[(kt)&1])    (8 HBM loads, 2 tiles ahead)
//   C: compute(cur)                  (MFMA)
//   D: vmcnt(8)  -> drains stores+reg(kt+1)+ts(kt+1), leaves reg(kt+2)
//   E: convwrite(kt+1)               (pack v -> LDS As + global Aext)
//   F: lgkmcnt(0); s_barrier
// x-prefetch gets 2 full iterations of cover instead of ~160cy.
__global__ void __launch_bounds__(256, 2) k_attn(const float* __restrict__ x,
                                                 const unsigned short* __restrict__ tokbf,
                                                 unsigned short* __restrict__ Aext) {
  __shared__ __align__(16) unsigned short smem[2 * 128 * 72 + 2 * 128 * 64];
  const int tid = threadIdx.x;
  const int wave = tid >> 6, lane = tid & 63;
  const int l15 = lane & 15, quad = lane >> 4;
  const int srow = lane >> 3, schunk = lane & 7;
  const int row0 = blockIdx.x * 128;
  const int trow = tid >> 1, thalf = tid & 1;
  const float* body = x + 8 * EMBED;
  const float* gxbase = body + (size_t)(row0 + trow) * EMBED + thalf * 32;

  f32x4 acc[2][8];
  const f32x4 zero = {0.f, 0.f, 0.f, 0.f};
  #pragma unroll
  for (int i = 0; i < 2; ++i)
    #pragma unroll
    for (int j = 0; j < 8; ++j) acc[i][j] = zero;

  float4 va[8], vb[8];

  auto regload = [&](int kt, float4* v) {
    const float* gx = gxbase + kt * 64;
    #pragma unroll
    for (int q = 0; q < 8; ++q) v[q] = *(const float4*)(gx + q * 4);
  };
  auto tsstage = [&](int buf, int kt) {
    unsigned short* Ts = smem + 2 * 128 * 72 + buf * (128 * 64);
    const int k0 = kt * 64;
    #pragma unroll
    for (int i = 0; i < 4; ++i) {
      const int r = i * 32 + wave * 8;
      async16(tokbf + (size_t)(r + srow) * EMBED + k0 + (schunk ^ srow) * 8, &Ts[r * 64]);
    }
  };
  auto convwrite = [&](int buf, int kt, const float4* v) {
    unsigned short* As = smem + buf * (128 * 72);
    unsigned int pk[16];
    #pragma unroll
    for (int q = 0; q < 8; ++q) {
      pk[q * 2]     = (unsigned int)f2bf(v[q].x) | ((unsigned int)f2bf(v[q].y) << 16);
      pk[q * 2 + 1] = (unsigned int)f2bf(v[q].z) | ((unsigned int)f2bf(v[q].w) << 16);
    }
    unsigned int* lw = (unsigned int*)&As[trow * 72 + thalf * 32];
    unsigned int* gw = (unsigned int*)(Aext + (size_t)(row0 + trow) * KEXT + kt * 64 + thalf * 32);
    #pragma unroll
    for (int q = 0; q < 4; ++q) {
      uint4 u; u.x = pk[q*4]; u.y = pk[q*4+1]; u.z = pk[q*4+2]; u.w = pk[q*4+3];
      ((uint4*)lw)[q] = u;
      ((uint4*)gw)[q] = u;
    }
  };
  auto compute = [&](int buf) {
    unsigned short* As = smem + buf * (128 * 72);
    unsigned short* Ts = smem + 2 * 128 * 72 + buf * (128 * 64);
    #pragma unroll
    for (int ks = 0; ks < 2; ++ks) {
      const int sw = ((ks * 4 + quad) ^ (l15 & 7)) * 8;
      bf16x8 a[2], b[8];
      #pragma unroll
      for (int i = 0; i < 2; ++i)
        a[i] = *(const bf16x8*)&As[(wave * 32 + i * 16 + l15) * 72 + ks * 32 + quad * 8];
      #pragma unroll
      for (int j = 0; j < 8; ++j)
        b[j] = *(const bf16x8*)&Ts[(j * 16 + l15) * 64 + sw];
      #pragma unroll
      for (int i = 0; i < 2; ++i)
        #pragma unroll
        for (int j = 0; j < 8; ++j)
          acc[i][j] = __builtin_amdgcn_mfma_f32_16x16x32_bf16(a[i], b[j], acc[i][j], 0, 0, 0);
    }
  };

  // prologue
  regload(0, va); tsstage(0, 0);
  asm volatile("s_waitcnt vmcnt(0)" ::: "memory");
  convwrite(0, 0, va);
  regload(1, vb);                                     // reg(1) -> vb
  asm volatile("s_waitcnt lgkmcnt(0)" ::: "memory");
  asm volatile("s_barrier" ::: "memory");

  #pragma unroll 1
  for (int kt = 0; kt < 16; ++kt) {
    const int cur = kt & 1;
    if (kt < 15) tsstage(cur ^ 1, kt + 1);            // 4 gload_lds
    if (kt < 14) {                                    // reg(kt+2) -> v[kt&1]
      if (cur) regload(kt + 2, vb); else regload(kt + 2, va);
    }
    compute(cur);
    if (kt < 15) {
      if (kt < 14) asm volatile("s_waitcnt vmcnt(8)" ::: "memory");
      else         asm volatile("s_waitcnt vmcnt(0)" ::: "memory");
      if (cur) convwrite(cur ^ 1, kt + 1, va);        // conv uses v[(kt+1)&1]
      else     convwrite(cur ^ 1, kt + 1, vb);
      asm volatile("s_waitcnt lgkmcnt(0)" ::: "memory");
    }
    asm volatile("s_barrier" ::: "memory");
  }

  unsigned short* Sc = smem;
  #pragma unroll
  for (int i = 0; i < 2; ++i) {
    #pragma unroll
    for (int r = 0; r < 4; ++r) {
      float mx = -1e30f;
      #pragma unroll
      for (int j = 0; j < 8; ++j) {
        const int c = j * 16 + l15;
        const float vv = acc[i][j][r] * 0.03125f;
        if (c < TOKLEN) mx = fmaxf(mx, vv);
      }
      #pragma unroll
      for (int d = 1; d < 16; d <<= 1) mx = fmaxf(mx, __shfl_xor(mx, d));
      float sm = 0.f;
      #pragma unroll
      for (int j = 0; j < 8; ++j) {
        const int c = j * 16 + l15;
        if (c < TOKLEN) sm += __expf(acc[i][j][r] * 0.03125f - mx);
      }
      #pragma unroll
      for (int d = 1; d < 16; d <<= 1) sm += __shfl_xor(sm, d);
      const float inv = 1.f / sm;
      const int row = wave * 32 + i * 16 + quad * 4 + r;
      #pragma unroll
      for (int j = 0; j < 8; ++j) {
        const int c = j * 16 + l15;
        const float p = (c < TOKLEN) ? __expf(acc[i][j][r] * 0.03125f - mx) * inv : 0.f;
        Sc[row * 128 + c] = f2bf(p);
      }
    }
  }
  __syncthreads();
  {
    const int r = tid >> 1, h = tid & 1;
    const uint4* src = (const uint4*)(Sc + r * 128 + h * 64);
    uint4* dst = (uint4*)(Aext + (size_t)(row0 + r) * KEXT + 1024 + h * 64);
    dst[0] = src[0]; dst[1] = src[1]; dst[2] = src[2]; dst[3] = src[3];
  }
}

// ---------------- main GEMM: 256x256 tile, fragment-reuse + counted vmcnt ----
// Per K-tile t (set s=t&1): 2 phases (B-frags held in regs; A per M-half).
// Boundary after phases: ISSUE(t+2 -> set s) THEN vmcnt(8) -> waits tile
// t+1's 8 loads (fully covered by this tile's compute), keeps t+2's 8 in
// flight. Queue never drains in the main loop (T4, m218).

#define MAIN_MFMA16(MH, KS)                                                     \
    acc[(MH)*4+0][0] = __builtin_amdgcn_mfma_f32_16x16x32_bf16(pa0##KS, pb0##KS, acc[(MH)*4+0][0], 0, 0, 0); \
    acc[(MH)*4+1][0] = __builtin_amdgcn_mfma_f32_16x16x32_bf16(pa1##KS, pb0##KS, acc[(MH)*4+1][0], 0, 0, 0); \
    acc[(MH)*4+2][0] = __builtin_amdgcn_mfma_f32_16x16x32_bf16(pa2##KS, pb0##KS, acc[(MH)*4+2][0], 0, 0, 0); \
    acc[(MH)*4+3][0] = __builtin_amdgcn_mfma_f32_16x16x32_bf16(pa3##KS, pb0##KS, acc[(MH)*4+3][0], 0, 0, 0); \
    acc[(MH)*4+0][1] = __builtin_amdgcn_mfma_f32_16x16x32_bf16(pa0##KS, pb1##KS, acc[(MH)*4+0][1], 0, 0, 0); \
    acc[(MH)*4+1][1] = __builtin_amdgcn_mfma_f32_16x16x32_bf16(pa1##KS, pb1##KS, acc[(MH)*4+1][1], 0, 0, 0); \
    acc[(MH)*4+2][1] = __builtin_amdgcn_mfma_f32_16x16x32_bf16(pa2##KS, pb1##KS, acc[(MH)*4+2][1], 0, 0, 0); \
    acc[(MH)*4+3][1] = __builtin_amdgcn_mfma_f32_16x16x32_bf16(pa3##KS, pb1##KS, acc[(MH)*4+3][1], 0, 0, 0); \
    acc[(MH)*4+0][2] = __builtin_amdgcn_mfma_f32_16x16x32_bf16(pa0##KS, pb2##KS, acc[(MH)*4+0][2], 0, 0, 0); \
    acc[(MH)*4+1][2] = __builtin_amdgcn_mfma_f32_16x16x32_bf16(pa1##KS, pb2##KS, acc[(MH)*4+1][2], 0, 0, 0); \
    acc[(MH)*4+2][2] = __builtin_amdgcn_mfma_f32_16x16x32_bf16(pa2##KS, pb2##KS, acc[(MH)*4+2][2], 0, 0, 0); \
    acc[(MH)*4+3][2] = __builtin_amdgcn_mfma_f32_16x16x32_bf16(pa3##KS, pb2##KS, acc[(MH)*4+3][2], 0, 0, 0); \
    acc[(MH)*4+0][3] = __builtin_amdgcn_mfma_f32_16x16x32_bf16(pa0##KS, pb3##KS, acc[(MH)*4+0][3], 0, 0, 0); \
    acc[(MH)*4+1][3] = __builtin_amdgcn_mfma_f32_16x16x32_bf16(pa1##KS, pb3##KS, acc[(MH)*4+1][3], 0, 0, 0); \
    acc[(MH)*4+2][3] = __builtin_amdgcn_mfma_f32_16x16x32_bf16(pa2##KS, pb3##KS, acc[(MH)*4+2][3], 0, 0, 0); \
    acc[(MH)*4+3][3] = __builtin_amdgcn_mfma_f32_16x16x32_bf16(pa3##KS, pb3##KS, acc[(MH)*4+3][3], 0, 0, 0);

#define MAIN_PHASE(S, MH, LOADB)                                                \
  do {                                                                          \
    const int sw0 = (quad ^ (l15 & 7)) * 8;                                     \
    const int sw1 = ((4 + quad) ^ (l15 & 7)) * 8;                               \
    const unsigned short* Ah = &Ab[S][wm][0];                                   \
    if (LOADB) {                                                                \
      const unsigned short* Bh = &Bb[S][bh][0];                                 \
      pb0_0 = *(const bf16x8*)&Bh[(brb + 0 * 16 + l15) * 64 + sw0];             \
      pb1_0 = *(const bf16x8*)&Bh[(brb + 1 * 16 + l15) * 64 + sw0];             \
      pb2_0 = *(const bf16x8*)&Bh[(brb + 2 * 16 + l15) * 64 + sw0];             \
      pb3_0 = *(const bf16x8*)&Bh[(brb + 3 * 16 + l15) * 64 + sw0];             \
      pb0_1 = *(const bf16x8*)&Bh[(brb + 0 * 16 + l15) * 64 + sw1];             \
      pb1_1 = *(const bf16x8*)&Bh[(brb + 1 * 16 + l15) * 64 + sw1];             \
      pb2_1 = *(const bf16x8*)&Bh[(brb + 2 * 16 + l15) * 64 + sw1];             \
      pb3_1 = *(const bf16x8*)&Bh[(brb + 3 * 16 + l15) * 64 + sw1];             \
    }                                                                           \
    bf16x8 pa0_0 = *(const bf16x8*)&Ah[((MH)*64 + 0 * 16 + l15) * 64 + sw0];    \
    bf16x8 pa1_0 = *(const bf16x8*)&Ah[((MH)*64 + 1 * 16 + l15) * 64 + sw0];    \
    bf16x8 pa2_0 = *(const bf16x8*)&Ah[((MH)*64 + 2 * 16 + l15) * 64 + sw0];    \
    bf16x8 pa3_0 = *(const bf16x8*)&Ah[((MH)*64 + 3 * 16 + l15) * 64 + sw0];    \
    bf16x8 pa0_1 = *(const bf16x8*)&Ah[((MH)*64 + 0 * 16 + l15) * 64 + sw1];    \
    bf16x8 pa1_1 = *(const bf16x8*)&Ah[((MH)*64 + 1 * 16 + l15) * 64 + sw1];    \
    bf16x8 pa2_1 = *(const bf16x8*)&Ah[((MH)*64 + 2 * 16 + l15) * 64 + sw1];    \
    bf16x8 pa3_1 = *(const bf16x8*)&Ah[((MH)*64 + 3 * 16 + l15) * 64 + sw1];    \
    asm volatile("s_barrier" ::: "memory");                                     \
    __builtin_amdgcn_s_setprio(1);                                              \
    MAIN_MFMA16(MH, _0)                                                         \
    MAIN_MFMA16(MH, _1)                                                         \
    __builtin_amdgcn_s_setprio(0);                                              \
    asm volatile("s_barrier" ::: "memory");                                     \
  } while (0)

#define ISSUE_TILE(KT, S)                                                       \
  do {                                                                          \
    const int k0_ = (KT) * 64;                                                  \
    _Pragma("unroll")                                                           \
    for (int h_ = 0; h_ < 2; ++h_) {                                            \
      _Pragma("unroll")                                                         \
      for (int r2_ = 0; r2_ < 2; ++r2_) {                                       \
        const int rb_ = r2_ * 64 + w8;                                          \
        async16(Aext + (size_t)(row0 + h_ * 128 + rb_ + srow) * KEXT + k0_ + (schunk ^ srow) * 8, \
                &Ab[S][h_][rb_ * 64]);                                          \
        async16(Bt + (size_t)(col0 + h_ * 128 + rb_ + srow) * KEXT + k0_ + (schunk ^ srow) * 8,   \
                &Bb[S][h_][rb_ * 64]);                                          \
      }                                                                         \
    }                                                                           \
  } while (0)

__global__ void __launch_bounds__(512) k_main(const unsigned short* __restrict__ Aext,
                                              const unsigned short* __restrict__ Bt,
                                              const float* __restrict__ x,
                                              const float* __restrict__ bfv,
                                              const float* __restrict__ scale,
                                              float* __restrict__ out) {
  __shared__ unsigned short Ab[2][2][128 * 64];   // [set][M-half][row*64+chunk]
  __shared__ unsigned short Bb[2][2][128 * 64];   // [set][N-half]
  const int tid = threadIdx.x;
  const int w = tid >> 6, lane = tid & 63;
  const int l15 = lane & 15, quad = lane >> 4;
  const int srow = lane >> 3, schunk = lane & 7;
  const int w8 = w * 8;
  const int wm = w >> 2, wn = w & 3;
  const int bh = wn >> 1, brb = (wn & 1) * 64;

  const int xcd = blockIdx.x & 7, slot = blockIdx.x >> 3;
  const int rt = (slot >> 2) * 8 + xcd;           // 0..127
  const int ct = slot & 3;                        // 0..3
  const int row0 = rt * 256;
  const int col0 = ct * 256;

  f32x4 acc[8][4];
  const f32x4 zero = {0.f, 0.f, 0.f, 0.f};
  #pragma unroll
  for (int i = 0; i < 8; ++i)
    #pragma unroll
    for (int j = 0; j < 4; ++j) acc[i][j] = zero;

  bf16x8 pb0_0, pb1_0, pb2_0, pb3_0, pb0_1, pb1_1, pb2_1, pb3_1;

  ISSUE_TILE(0, 0);
  ISSUE_TILE(1, 1);
  asm volatile("s_waitcnt vmcnt(8)" ::: "memory");  // tile0 ready, tile1 in flight
  asm volatile("s_barrier" ::: "memory");
  #pragma unroll 1
  for (int i = 0; i < 9; ++i) {
    // ---- K-tile 2i (set0): compute, then issue 2i+2, wait 2i+1 ----
    MAIN_PHASE(0, 0, 1);
    MAIN_PHASE(0, 1, 0);
    if (i < 8) {
      ISSUE_TILE(2 * i + 2, 0);
      asm volatile("s_waitcnt vmcnt(8)" ::: "memory");
    } else {
      asm volatile("s_waitcnt vmcnt(0)" ::: "memory");
    }
    asm volatile("s_barrier" ::: "memory");
    // ---- K-tile 2i+1 (set1): compute, then issue 2i+3, wait 2i+2 ----
    MAIN_PHASE(1, 0, 1);
    MAIN_PHASE(1, 1, 0);
    if (i < 8) {
      ISSUE_TILE(2 * i + 3, 1);
      asm volatile("s_waitcnt vmcnt(8)" ::: "memory");
      asm volatile("s_barrier" ::: "memory");
    }
    // i==8: last tile done; fall through to epilogue
  }

  const float s = scale[0];
  #pragma unroll
  for (int mf = 0; mf < 8; ++mf) {
    const int rb = row0 + wm * 128 + mf * 16 + quad * 4;
    #pragma unroll
    for (int nf = 0; nf < 4; ++nf) {
      const int c = col0 + wn * 64 + nf * 16 + l15;
      const float bfc = bfv[c];
      #pragma unroll
      for (int r = 0; r < 4; ++r) {
        const size_t idx = (size_t)(rb + r + 8) * EMBED + c;
        out[idx] = x[idx] + (acc[mf][nf][r] + bfc) * s;
      }
    }
  }
}

extern "C" void kernel_launch(void* const* d_in, const int* in_sizes, int n_in,
                              void* d_out, int out_size, void* d_ws, size_t ws_size,
                              hipStream_t stream) {
  const float* x     = (const float*)d_in[0];
  const int*   layer = (const int*)d_in[1];
  const float* A     = (const float*)d_in[2];
  const float* B     = (const float*)d_in[3];
  const float* Wd    = (const float*)d_in[4];
  const float* bd    = (const float*)d_in[5];
  const float* Wu    = (const float*)d_in[6];
  const float* bu    = (const float*)d_in[7];
  const float* Wt    = (const float*)d_in[8];
  const float* bt    = (const float*)d_in[9];
  const float* Wf    = (const float*)d_in[10];
  const float* bf    = (const float*)d_in[11];
  const float* scale = (const float*)d_in[12];
  float* out = (float*)d_out;

  char* ws = (char*)d_ws;
  unsigned short* Aext    = (unsigned short*)(ws + 0);          // 32768*1152*2
  unsigned short* wtbf    = (unsigned short*)(ws + 0);          // alias (dead before k_attn)
  unsigned short* wfbf    = (unsigned short*)(ws + 2097152);    // alias
  unsigned short* Bt_     = (unsigned short*)(ws + 75497472);   // 1024*1152*2
  unsigned short* tokbf   = (unsigned short*)(ws + 77856768);   // 128*1024*2
  float*          G       = (float*)(ws + 78118912);            // 1024*128*4
  float*          AG      = (float*)(ws + 78643200);            // 100*128*4
  float*          asum    = (float*)(ws + 78694400);            // 128*4
  float*          wfbt    = (float*)(ws + 78694912);            // 1024*4
  unsigned short* tfeatbf = (unsigned short*)(ws + 78699008);   // 128*1024*2

  k_gelu  <<<512, 256, 0, stream>>>(B, layer, Wd, bd, G);
  k_ag    <<<100, 128, 0, stream>>>(A, G, AG, asum);
  k_tokens<<<128, 256, 0, stream>>>(AG, asum, Wu, bu, tokbf);
  k_wprep <<<1024, 256, 0, stream>>>(Wf, Wt, bt, x, out, Bt_, wfbf, wtbf, wfbt);
  k_tf1   <<<8, 256, 0, stream>>>(tokbf, wtbf, tfeatbf);
  k_tf2   <<<8, 256, 0, stream>>>(wfbf, tfeatbf, wfbt, Bt_);
  k_attn  <<<256, 256, 0, stream>>>(x, tokbf, Aext);
  k_main  <<<512, 512, 0, stream>>>(Aext, Bt_, x, bf, scale, out);
}